// Round 9
// baseline (128.292 us; speedup 1.0000x reference)
//
#include <hip/hip_runtime.h>
#include <math.h>

#define N_ATOMS 512
#define N_MOL   16
#define HIDDEN  128
#define FILTERS 128
#define NUM_RBF 50
#define CUTOFF  10.0f
#define N_LAYERS 3

#define KBINS  1024              // lerp bins over [0, CUTOFF]
#define NBINS  1026              // bins evaluated 0..1025 (>=1024 give env=0)
#define PROWS  (KBINS + 1)       // pair rows 0..1024; row k = {phi_k, phi_{k+1}} bf16
#define PAIRS  513               // bin-pairs per layer (2 bins per wave)
#define TOTW2  (N_LAYERS * PAIRS)        // 1539 table wave-units
#define TWBLK  ((TOTW2 + 7) / 8)         // 193 table blocks (8 waves each)
#define EMBB   8                         // emb blocks, 64 atoms each
#define PI_F   3.14159265358979f

__device__ __forceinline__ unsigned short f2bf(float v) {
    unsigned u = __float_as_uint(v);
    u += 0x7fffu + ((u >> 16) & 1u);     // round-to-nearest-even
    return (unsigned short)(u >> 16);
}

// ============ front: filter tables (2 bins per wave) ∥ embedding+xj0 ============
__global__ void __launch_bounds__(512) k_front(
        const int* __restrict__ an, const float* __restrict__ emb,
        const float* __restrict__ d1w, const float* __restrict__ d1b,
        const float* __restrict__ fw1, const float* __restrict__ fb1,
        const float* __restrict__ fw2, const float* __restrict__ fb2,
        float* __restrict__ x, unsigned short* __restrict__ xj,
        unsigned short* __restrict__ tab, float* __restrict__ molsum,
        int* __restrict__ done) {
    __shared__ float s_sh[8][2][HIDDEN];               // 8 KB (table role)
    __shared__ __align__(16) float s_row[64][HIDDEN];  // 32 KB (emb role)
    __shared__ int   s_an[64];
    int bid = blockIdx.x, t = threadIdx.x;

    if (bid == 0) {                                    // zero pool accumulators each call
        for (int idx = t; idx < N_MOL * HIDDEN; idx += 512) molsum[idx] = 0.f;
        if (t == 0) *done = 0;
    }

    if (bid < TWBLK) {
        int wv = t >> 6, lane = t & 63;
        int u  = bid * 8 + wv;
        int uc = u < TOTW2 ? u : TOTW2 - 1;            // clamp idle waves
        int l  = uc / PAIRS;
        int pr = uc - l * PAIRS;
        int binA = 2 * pr, binB = binA + 1;            // binB <= 1025
        float dA = binA * (CUTOFF / (float)KBINS);
        float dB = binB * (CUTOFF / (float)KBINS);
        const float* w1g = fw1 + (size_t)l * NUM_RBF * FILTERS;
        const float* w2g = fw2 + (size_t)l * FILTERS * FILTERS;
        int c0 = lane, c1 = lane + 64;
        float hA0 = fb1[l * FILTERS + c0], hA1 = fb1[l * FILTERS + c1];
        float hB0 = hA0, hB1 = hA1;
        #pragma unroll 5
        for (int r = 0; r < NUM_RBF; r++) {
            float cr = r * (CUTOFF / (float)(NUM_RBF - 1));
            float xa = dA - cr, xb = dB - cr;
            float rbA = __expf(-xa * xa * 12.5f);      // 1/(2*w^2), w = 0.2
            float rbB = __expf(-xb * xb * 12.5f);
            float w0 = w1g[r * FILTERS + c0];
            float w1v = w1g[r * FILTERS + c1];
            hA0 = fmaf(rbA, w0, hA0);  hA1 = fmaf(rbA, w1v, hA1);
            hB0 = fmaf(rbB, w0, hB0);  hB1 = fmaf(rbB, w1v, hB1);
        }
        s_sh[wv][0][c0] = hA0 / (1.f + __expf(-hA0));  // silu
        s_sh[wv][0][c1] = hA1 / (1.f + __expf(-hA1));
        s_sh[wv][1][c0] = hB0 / (1.f + __expf(-hB0));
        s_sh[wv][1][c1] = hB1 / (1.f + __expf(-hB1));
        __syncthreads();
        float oA0 = fb2[l * FILTERS + c0], oA1 = fb2[l * FILTERS + c1];
        float oB0 = oA0, oB1 = oA1;
        #pragma unroll 4
        for (int hh = 0; hh < FILTERS; hh++) {
            float w0 = w2g[hh * FILTERS + c0];
            float w1v = w2g[hh * FILTERS + c1];
            float hvA = s_sh[wv][0][hh];
            float hvB = s_sh[wv][1][hh];
            oA0 = fmaf(hvA, w0, oA0);  oA1 = fmaf(hvA, w1v, oA1);
            oB0 = fmaf(hvB, w0, oB0);  oB1 = fmaf(hvB, w1v, oB1);
        }
        float envA = (binA >= KBINS) ? 0.f : 0.5f * (__cosf(dA * (PI_F / CUTOFF)) + 1.f);
        float envB = (binB >= KBINS) ? 0.f : 0.5f * (__cosf(dB * (PI_F / CUTOFF)) + 1.f);
        unsigned short pA0 = f2bf(oA0 * envA), pA1 = f2bf(oA1 * envA);
        unsigned short pB0 = f2bf(oB0 * envB), pB1 = f2bf(oB1 * envB);
        size_t base = (size_t)l * PROWS * FILTERS * 2;
        if (u < TOTW2) {
            if (binA <= KBINS) {                       // x-entries of row binA
                tab[base + ((size_t)binA * FILTERS + c0) * 2 + 0] = pA0;
                tab[base + ((size_t)binA * FILTERS + c1) * 2 + 0] = pA1;
            }
            if (binA >= 1) {                           // y-entries of row binA-1
                tab[base + ((size_t)(binA - 1) * FILTERS + c0) * 2 + 1] = pA0;
                tab[base + ((size_t)(binA - 1) * FILTERS + c1) * 2 + 1] = pA1;
            }
            if (binB <= KBINS) {
                tab[base + ((size_t)binB * FILTERS + c0) * 2 + 0] = pB0;
                tab[base + ((size_t)binB * FILTERS + c1) * 2 + 0] = pB1;
            }
            // binB >= 1 always
            tab[base + ((size_t)(binB - 1) * FILTERS + c0) * 2 + 1] = pB0;
            tab[base + ((size_t)(binB - 1) * FILTERS + c1) * 2 + 1] = pB1;
        }
    } else {
        int eb = bid - TWBLK;
        int i0 = eb * 64;
        if (t < 64) s_an[t] = an[i0 + t];
        __syncthreads();
        for (int idx = t; idx < 64 * HIDDEN; idx += 512) {
            int a = idx >> 7, c = idx & 127;
            float v = emb[(size_t)s_an[a] * HIDDEN + c];
            s_row[a][c] = v;
            x[(size_t)(i0 + a) * HIDDEN + c] = v;
        }
        __syncthreads();
        int cq = t & 31, ag = t >> 5;
        float o[4][4];
        float4 bv = *(const float4*)(d1b + 4 * cq);
        float bva[4] = { bv.x, bv.y, bv.z, bv.w };
        #pragma unroll
        for (int aa = 0; aa < 4; aa++)
            #pragma unroll
            for (int cc = 0; cc < 4; cc++) o[aa][cc] = bva[cc];
        #pragma unroll 4
        for (int h = 0; h < HIDDEN; h += 2) {
            float4 wA = *(const float4*)(d1w + (size_t)h * FILTERS + 4 * cq);
            float4 wB = *(const float4*)(d1w + (size_t)(h + 1) * FILTERS + 4 * cq);
            float wa[4] = { wA.x, wA.y, wA.z, wA.w };
            float wb[4] = { wB.x, wB.y, wB.z, wB.w };
            #pragma unroll
            for (int aa = 0; aa < 4; aa++) {
                float2 hp = *(const float2*)(&s_row[ag * 4 + aa][h]);
                #pragma unroll
                for (int cc = 0; cc < 4; cc++) {
                    o[aa][cc] = fmaf(hp.x, wa[cc], o[aa][cc]);
                    o[aa][cc] = fmaf(hp.y, wb[cc], o[aa][cc]);
                }
            }
        }
        #pragma unroll
        for (int aa = 0; aa < 4; aa++) {
            int i = i0 + ag * 4 + aa;
            #pragma unroll
            for (int cp = 0; cp < 2; cp++) {
                unsigned int pk = (unsigned)f2bf(o[aa][2 * cp]) |
                                  ((unsigned)f2bf(o[aa][2 * cp + 1]) << 16);
                *(unsigned int*)(xj + (size_t)i * FILTERS + 4 * cq + 2 * cp) = pk;
            }
        }
    }
}

// ======== layer kernel (R8 structure); LAST also does pool via atomics + spin ========
template<int LAST>
__global__ void __launch_bounds__(512) k_layer(const float* __restrict__ pos,
        const unsigned int* __restrict__ tabl, const unsigned short* __restrict__ xj_in,
        float* __restrict__ x, const float* __restrict__ w2, const float* __restrict__ b2,
        const float* __restrict__ w1n, const float* __restrict__ b1n,
        unsigned short* __restrict__ xj_out,
        const int* __restrict__ batch, float* __restrict__ molsum, int* __restrict__ done,
        const float* __restrict__ ow1, const float* __restrict__ ob1,
        const float* __restrict__ ow2, const float* __restrict__ ob2,
        float* __restrict__ out) {
    int j = blockIdx.x;
    int t = threadIdx.x;
    int wv = t >> 6, e = t & 63;
    __shared__ float  s_pos[N_ATOMS * 3];
    __shared__ float2 s_kw[N_ATOMS];
    __shared__ float  s_part[8][FILTERS];
    __shared__ float  s_red[4][FILTERS];
    __shared__ float  s_agg[FILTERS];
    __shared__ float  s_xn[HIDDEN];
    __shared__ int    s_cnt;
    for (int idx = t; idx < N_ATOMS * 3; idx += 512) s_pos[idx] = pos[idx];
    __syncthreads();
    {   // one distance per thread
        float pjx = s_pos[j*3+0], pjy = s_pos[j*3+1], pjz = s_pos[j*3+2];
        float dx = s_pos[t*3+0] - pjx;
        float dy = s_pos[t*3+1] - pjy;
        float dz = s_pos[t*3+2] - pjz;
        float d  = sqrtf(dx*dx + dy*dy + dz*dz);
        int k; float w;
        if (t == j || d >= CUTOFF) { k = KBINS; w = 0.f; }
        else {
            float tt = d * ((float)KBINS / CUTOFF);
            k = (int)tt;
            if (k > KBINS - 1) k = KBINS - 1;
            w = tt - (float)k;
        }
        s_kw[t] = make_float2(w, __int_as_float(k));
    }
    __syncthreads();
    // ---- aggregation: 64 i per wave, 2 channels per lane ----
    const uint2*        tab2 = (const uint2*)tabl;
    const unsigned int* xju  = (const unsigned int*)xj_in;
    float ae0 = 0.f, ao0 = 0.f, ae1 = 0.f, ao1 = 0.f;
    int i0 = wv * 64;
    #pragma unroll 4
    for (int ii = 0; ii < 64; ii += 2) {
        float2 kv0 = s_kw[i0 + ii];
        float2 kv1 = s_kw[i0 + ii + 1];
        uint2 p0 = tab2[(size_t)__float_as_int(kv0.y) * 64 + e];
        uint2 p1 = tab2[(size_t)__float_as_int(kv1.y) * 64 + e];
        unsigned int xu0 = xju[(size_t)(i0 + ii    ) * 64 + e];
        unsigned int xu1 = xju[(size_t)(i0 + ii + 1) * 64 + e];
        float xe0 = __uint_as_float(xu0 << 16), xo0 = __uint_as_float(xu0 & 0xffff0000u);
        float xe1 = __uint_as_float(xu1 << 16), xo1 = __uint_as_float(xu1 & 0xffff0000u);
        float le0 = __uint_as_float(p0.x << 16), he0 = __uint_as_float(p0.x & 0xffff0000u);
        float lo0 = __uint_as_float(p0.y << 16), ho0 = __uint_as_float(p0.y & 0xffff0000u);
        float le1 = __uint_as_float(p1.x << 16), he1 = __uint_as_float(p1.x & 0xffff0000u);
        float lo1 = __uint_as_float(p1.y << 16), ho1 = __uint_as_float(p1.y & 0xffff0000u);
        ae0 = fmaf(xe0, fmaf(kv0.x, he0 - le0, le0), ae0);
        ao0 = fmaf(xo0, fmaf(kv0.x, ho0 - lo0, lo0), ao0);
        ae1 = fmaf(xe1, fmaf(kv1.x, he1 - le1, le1), ae1);
        ao1 = fmaf(xo1, fmaf(kv1.x, ho1 - lo1, lo1), ao1);
    }
    s_part[wv][2 * e]     = ae0 + ae1;
    s_part[wv][2 * e + 1] = ao0 + ao1;
    __syncthreads();
    if (t < FILTERS) {
        float s = 0.f;
        #pragma unroll
        for (int w8 = 0; w8 < 8; w8++) s += s_part[w8][t];
        s_agg[t] = s;
    }
    __syncthreads();
    // ---- x update ----
    int c = t & 127, seg = t >> 7;
    float v = 0.f;
    #pragma unroll 8
    for (int ff = seg * 32; ff < seg * 32 + 32; ff++)
        v = fmaf(s_agg[ff], w2[(size_t)ff * HIDDEN + c], v);
    s_red[seg][c] = v;
    __syncthreads();
    float xnew = 0.f;
    if (seg == 0) {
        xnew = x[(size_t)j * HIDDEN + c] + b2[c]
             + s_red[0][c] + s_red[1][c] + s_red[2][c] + s_red[3][c];
        x[(size_t)j * HIDDEN + c] = xnew;
        s_xn[c] = xnew;
    }
    __syncthreads();
    if (!LAST) {
        float a2 = 0.f;
        #pragma unroll 8
        for (int hh = seg * 32; hh < seg * 32 + 32; hh++)
            a2 = fmaf(s_xn[hh], w1n[(size_t)hh * FILTERS + c], a2);
        s_red[seg][c] = a2;
        __syncthreads();
        if (seg == 0)
            xj_out[(size_t)j * FILTERS + c] =
                f2bf(b1n[c] + s_red[0][c] + s_red[1][c] + s_red[2][c] + s_red[3][c]);
    } else {
        // ---- pool: accumulate this row into molsum, bump counter, exit (j>=16) ----
        if (seg == 0) atomicAdd(&molsum[(size_t)batch[j] * HIDDEN + c], xnew);
        __threadfence();
        __syncthreads();
        if (t == 0) atomicAdd(done, 1);
        if (j < N_MOL) {
            int m = j;
            if (t == 0) {
                while (atomicAdd(done, 0) < N_ATOMS) __builtin_amdgcn_s_sleep(16);
                s_cnt = 0;
            }
            __syncthreads();
            atomicAdd(&s_cnt, (batch[t] == m) ? 1 : 0);
            __syncthreads();
            int cnt = s_cnt;
            if (t < HIDDEN)
                s_xn[t] = atomicAdd(&molsum[(size_t)m * HIDDEN + t], 0.f)
                        / (float)(cnt > 0 ? cnt : 1);
            __syncthreads();
            // MLP1: 64 outputs x 8 slices of 16 terms
            int o = t & 63, sl = t >> 6;
            float a = 0.f;
            #pragma unroll 8
            for (int h = sl * 16; h < sl * 16 + 16; h++)
                a = fmaf(s_xn[h], ow1[h * 64 + o], a);
            float* sr = (float*)s_part;               // reuse as [8][64]
            sr[sl * 64 + o] = a;
            __syncthreads();
            if (t < 64) {
                float vv = ob1[t];
                #pragma unroll
                for (int s8 = 0; s8 < 8; s8++) vv += sr[s8 * 64 + t];
                float hh = vv / (1.f + __expf(-vv));  // silu
                float d2 = hh * ow2[t];
                for (int off = 32; off > 0; off >>= 1) d2 += __shfl_down(d2, off, 64);
                if (t == 0) out[m] = d2 + ob2[0];
            }
        }
    }
}

extern "C" void kernel_launch(void* const* d_in, const int* in_sizes, int n_in,
                              void* d_out, int out_size, void* d_ws, size_t ws_size,
                              hipStream_t stream) {
    const int*   an    = (const int*)  d_in[0];
    const float* pos   = (const float*)d_in[1];
    const int*   batch = (const int*)  d_in[2];
    const float* emb   = (const float*)d_in[3];
    const float* fw1   = (const float*)d_in[4];
    const float* fb1   = (const float*)d_in[5];
    const float* fw2   = (const float*)d_in[6];
    const float* fb2   = (const float*)d_in[7];
    const float* d1w   = (const float*)d_in[8];
    const float* d1b   = (const float*)d_in[9];
    const float* d2w   = (const float*)d_in[10];
    const float* d2b   = (const float*)d_in[11];
    const float* ow1   = (const float*)d_in[12];
    const float* ob1   = (const float*)d_in[13];
    const float* ow2   = (const float*)d_in[14];
    const float* ob2   = (const float*)d_in[15];
    float* out = (float*)d_out;

    float*          x    = (float*)d_ws;                               // 256 KB
    unsigned short* xjA  = (unsigned short*)(x + N_ATOMS * HIDDEN);    // 128 KB
    unsigned short* xjB  = xjA + (size_t)N_ATOMS * FILTERS;            // 128 KB
    unsigned short* tab  = xjB + (size_t)N_ATOMS * FILTERS;            // 1.575 MB
    float*          mols = (float*)(tab + (size_t)N_LAYERS * PROWS * FILTERS * 2);
    int*            done = (int*)(mols + N_MOL * HIDDEN);

    k_front<<<TWBLK + EMBB, 512, 0, stream>>>(
        an, emb, d1w, d1b, fw1, fb1, fw2, fb2, x, xjA, tab, mols, done);

    const unsigned int* t0 = (const unsigned int*)(tab + (size_t)0 * PROWS * FILTERS * 2);
    const unsigned int* t1 = (const unsigned int*)(tab + (size_t)1 * PROWS * FILTERS * 2);
    const unsigned int* t2 = (const unsigned int*)(tab + (size_t)2 * PROWS * FILTERS * 2);

    k_layer<0><<<N_ATOMS, 512, 0, stream>>>(pos, t0, xjA, x,
        d2w + (size_t)0*FILTERS*HIDDEN, d2b + (size_t)0*HIDDEN,
        d1w + (size_t)1*HIDDEN*FILTERS, d1b + (size_t)1*FILTERS, xjB,
        batch, mols, done, ow1, ob1, ow2, ob2, out);
    k_layer<0><<<N_ATOMS, 512, 0, stream>>>(pos, t1, xjB, x,
        d2w + (size_t)1*FILTERS*HIDDEN, d2b + (size_t)1*HIDDEN,
        d1w + (size_t)2*HIDDEN*FILTERS, d1b + (size_t)2*FILTERS, xjA,
        batch, mols, done, ow1, ob1, ow2, ob2, out);
    k_layer<1><<<N_ATOMS, 512, 0, stream>>>(pos, t2, xjA, x,
        d2w + (size_t)2*FILTERS*HIDDEN, d2b + (size_t)2*HIDDEN,
        d1w, d1b, xjB,
        batch, mols, done, ow1, ob1, ow2, ob2, out);
}

// Round 10
// 69.492 us; speedup vs baseline: 1.8461x; 1.8461x over previous
//
#include <hip/hip_runtime.h>
#include <math.h>

#define N_ATOMS 512
#define N_MOL   16
#define HIDDEN  128
#define FILTERS 128
#define NUM_RBF 50
#define CUTOFF  10.0f
#define N_LAYERS 3

#define KBINS  1024              // lerp bins over [0, CUTOFF]
#define PROWS  (KBINS + 1)       // pair rows 0..1024; row k = {phi_k, phi_{k+1}} bf16
#define PAIRS  513               // bin-pairs per layer (2 bins per wave)
#define TOTW2  (N_LAYERS * PAIRS)        // 1539 table wave-units
#define TWBLK  ((TOTW2 + 7) / 8)         // 193 table blocks (8 waves each)
#define EMBB   8                         // emb blocks, 64 atoms each
#define PI_F   3.14159265358979f

__device__ __forceinline__ unsigned short f2bf(float v) {
    unsigned u = __float_as_uint(v);
    u += 0x7fffu + ((u >> 16) & 1u);     // round-to-nearest-even
    return (unsigned short)(u >> 16);
}

// ============ front: filter tables (2 bins per wave) ∥ embedding+xj0 ============
__global__ void __launch_bounds__(512) k_front(
        const int* __restrict__ an, const float* __restrict__ emb,
        const float* __restrict__ d1w, const float* __restrict__ d1b,
        const float* __restrict__ fw1, const float* __restrict__ fb1,
        const float* __restrict__ fw2, const float* __restrict__ fb2,
        float* __restrict__ x, unsigned short* __restrict__ xj,
        unsigned short* __restrict__ tab) {
    __shared__ float s_sh[8][2][HIDDEN];               // 8 KB (table role)
    __shared__ __align__(16) float s_row[64][HIDDEN];  // 32 KB (emb role)
    __shared__ int   s_an[64];
    int bid = blockIdx.x, t = threadIdx.x;

    if (bid < TWBLK) {
        int wv = t >> 6, lane = t & 63;
        int u  = bid * 8 + wv;
        int uc = u < TOTW2 ? u : TOTW2 - 1;            // clamp idle waves
        int l  = uc / PAIRS;
        int pr = uc - l * PAIRS;
        int binA = 2 * pr, binB = binA + 1;            // binB <= 1025
        float dA = binA * (CUTOFF / (float)KBINS);
        float dB = binB * (CUTOFF / (float)KBINS);
        const float* w1g = fw1 + (size_t)l * NUM_RBF * FILTERS;
        const float* w2g = fw2 + (size_t)l * FILTERS * FILTERS;
        int c0 = lane, c1 = lane + 64;
        float hA0 = fb1[l * FILTERS + c0], hA1 = fb1[l * FILTERS + c1];
        float hB0 = hA0, hB1 = hA1;
        #pragma unroll 5
        for (int r = 0; r < NUM_RBF; r++) {
            float cr = r * (CUTOFF / (float)(NUM_RBF - 1));
            float xa = dA - cr, xb = dB - cr;
            float rbA = __expf(-xa * xa * 12.5f);      // 1/(2*w^2), w = 0.2
            float rbB = __expf(-xb * xb * 12.5f);
            float w0 = w1g[r * FILTERS + c0];
            float w1v = w1g[r * FILTERS + c1];
            hA0 = fmaf(rbA, w0, hA0);  hA1 = fmaf(rbA, w1v, hA1);
            hB0 = fmaf(rbB, w0, hB0);  hB1 = fmaf(rbB, w1v, hB1);
        }
        s_sh[wv][0][c0] = hA0 / (1.f + __expf(-hA0));  // silu
        s_sh[wv][0][c1] = hA1 / (1.f + __expf(-hA1));
        s_sh[wv][1][c0] = hB0 / (1.f + __expf(-hB0));
        s_sh[wv][1][c1] = hB1 / (1.f + __expf(-hB1));
        __syncthreads();
        float oA0 = fb2[l * FILTERS + c0], oA1 = fb2[l * FILTERS + c1];
        float oB0 = oA0, oB1 = oA1;
        #pragma unroll 4
        for (int hh = 0; hh < FILTERS; hh++) {
            float w0 = w2g[hh * FILTERS + c0];
            float w1v = w2g[hh * FILTERS + c1];
            float hvA = s_sh[wv][0][hh];
            float hvB = s_sh[wv][1][hh];
            oA0 = fmaf(hvA, w0, oA0);  oA1 = fmaf(hvA, w1v, oA1);
            oB0 = fmaf(hvB, w0, oB0);  oB1 = fmaf(hvB, w1v, oB1);
        }
        float envA = (binA >= KBINS) ? 0.f : 0.5f * (__cosf(dA * (PI_F / CUTOFF)) + 1.f);
        float envB = (binB >= KBINS) ? 0.f : 0.5f * (__cosf(dB * (PI_F / CUTOFF)) + 1.f);
        unsigned short pA0 = f2bf(oA0 * envA), pA1 = f2bf(oA1 * envA);
        unsigned short pB0 = f2bf(oB0 * envB), pB1 = f2bf(oB1 * envB);
        size_t base = (size_t)l * PROWS * FILTERS * 2;
        if (u < TOTW2) {
            if (binA <= KBINS) {
                tab[base + ((size_t)binA * FILTERS + c0) * 2 + 0] = pA0;
                tab[base + ((size_t)binA * FILTERS + c1) * 2 + 0] = pA1;
            }
            if (binA >= 1) {
                tab[base + ((size_t)(binA - 1) * FILTERS + c0) * 2 + 1] = pA0;
                tab[base + ((size_t)(binA - 1) * FILTERS + c1) * 2 + 1] = pA1;
            }
            if (binB <= KBINS) {
                tab[base + ((size_t)binB * FILTERS + c0) * 2 + 0] = pB0;
                tab[base + ((size_t)binB * FILTERS + c1) * 2 + 0] = pB1;
            }
            tab[base + ((size_t)(binB - 1) * FILTERS + c0) * 2 + 1] = pB0;   // binB>=1 always
            tab[base + ((size_t)(binB - 1) * FILTERS + c1) * 2 + 1] = pB1;
        }
    } else {
        int eb = bid - TWBLK;
        int i0 = eb * 64;
        if (t < 64) s_an[t] = an[i0 + t];
        __syncthreads();
        for (int idx = t; idx < 64 * HIDDEN; idx += 512) {
            int a = idx >> 7, c = idx & 127;
            float v = emb[(size_t)s_an[a] * HIDDEN + c];
            s_row[a][c] = v;
            x[(size_t)(i0 + a) * HIDDEN + c] = v;
        }
        __syncthreads();
        int cq = t & 31, ag = t >> 5;
        float o[4][4];
        float4 bv = *(const float4*)(d1b + 4 * cq);
        float bva[4] = { bv.x, bv.y, bv.z, bv.w };
        #pragma unroll
        for (int aa = 0; aa < 4; aa++)
            #pragma unroll
            for (int cc = 0; cc < 4; cc++) o[aa][cc] = bva[cc];
        #pragma unroll 4
        for (int h = 0; h < HIDDEN; h += 2) {
            float4 wA = *(const float4*)(d1w + (size_t)h * FILTERS + 4 * cq);
            float4 wB = *(const float4*)(d1w + (size_t)(h + 1) * FILTERS + 4 * cq);
            float wa[4] = { wA.x, wA.y, wA.z, wA.w };
            float wb[4] = { wB.x, wB.y, wB.z, wB.w };
            #pragma unroll
            for (int aa = 0; aa < 4; aa++) {
                float2 hp = *(const float2*)(&s_row[ag * 4 + aa][h]);
                #pragma unroll
                for (int cc = 0; cc < 4; cc++) {
                    o[aa][cc] = fmaf(hp.x, wa[cc], o[aa][cc]);
                    o[aa][cc] = fmaf(hp.y, wb[cc], o[aa][cc]);
                }
            }
        }
        #pragma unroll
        for (int aa = 0; aa < 4; aa++) {
            int i = i0 + ag * 4 + aa;
            #pragma unroll
            for (int cp = 0; cp < 2; cp++) {
                unsigned int pk = (unsigned)f2bf(o[aa][2 * cp]) |
                                  ((unsigned)f2bf(o[aa][2 * cp + 1]) << 16);
                *(unsigned int*)(xj + (size_t)i * FILTERS + 4 * cq + 2 * cp) = pk;
            }
        }
    }
}

// ======== layer kernel: one j per block; direct pos reads; unroll-8 gather ========
template<int LAST>
__global__ void __launch_bounds__(512) k_layer(const float* __restrict__ pos,
        const unsigned int* __restrict__ tabl, const unsigned short* __restrict__ xj_in,
        float* __restrict__ x, const float* __restrict__ w2, const float* __restrict__ b2,
        const float* __restrict__ w1n, const float* __restrict__ b1n,
        unsigned short* __restrict__ xj_out) {
    int j = blockIdx.x;
    int t = threadIdx.x;
    int wv = t >> 6, e = t & 63;
    __shared__ float2 s_kw[N_ATOMS];
    __shared__ float  s_part[8][FILTERS];
    __shared__ float  s_red[4][FILTERS];
    __shared__ float  s_agg[FILTERS];
    __shared__ float  s_xn[HIDDEN];
    int c = t & 127, seg = t >> 7;
    float xold = (seg == 0) ? x[(size_t)j * HIDDEN + c] : 0.f;   // early load
    {   // one distance per thread, straight from global (pos is L2-hot)
        float pjx = pos[3*j], pjy = pos[3*j+1], pjz = pos[3*j+2];
        float dx = pos[3*t] - pjx;
        float dy = pos[3*t+1] - pjy;
        float dz = pos[3*t+2] - pjz;
        float d  = sqrtf(dx*dx + dy*dy + dz*dz);
        int k; float w;
        if (t == j || d >= CUTOFF) { k = KBINS; w = 0.f; }
        else {
            float tt = d * ((float)KBINS / CUTOFF);
            k = (int)tt;
            if (k > KBINS - 1) k = KBINS - 1;
            w = tt - (float)k;
        }
        s_kw[t] = make_float2(w, __int_as_float(k));
    }
    __syncthreads();
    // ---- aggregation: 64 i per wave, 2 channels per lane, 8-deep load issue ----
    const uint2*        tab2 = (const uint2*)tabl;
    const unsigned int* xju  = (const unsigned int*)xj_in;
    float ae0 = 0.f, ao0 = 0.f, ae1 = 0.f, ao1 = 0.f;
    int i0 = wv * 64;
    for (int ii = 0; ii < 64; ii += 8) {
        float2 kv[8]; uint2 p[8]; unsigned int xu[8];
        #pragma unroll
        for (int r = 0; r < 8; r++) kv[r] = s_kw[i0 + ii + r];
        #pragma unroll
        for (int r = 0; r < 8; r++) p[r] = tab2[(size_t)__float_as_int(kv[r].y) * 64 + e];
        #pragma unroll
        for (int r = 0; r < 8; r++) xu[r] = xju[(size_t)(i0 + ii + r) * 64 + e];
        #pragma unroll
        for (int r = 0; r < 8; r += 2) {
            float xe0 = __uint_as_float(xu[r]   << 16), xo0 = __uint_as_float(xu[r]   & 0xffff0000u);
            float xe1 = __uint_as_float(xu[r+1] << 16), xo1 = __uint_as_float(xu[r+1] & 0xffff0000u);
            float le0 = __uint_as_float(p[r].x   << 16), he0 = __uint_as_float(p[r].x   & 0xffff0000u);
            float lo0 = __uint_as_float(p[r].y   << 16), ho0 = __uint_as_float(p[r].y   & 0xffff0000u);
            float le1 = __uint_as_float(p[r+1].x << 16), he1 = __uint_as_float(p[r+1].x & 0xffff0000u);
            float lo1 = __uint_as_float(p[r+1].y << 16), ho1 = __uint_as_float(p[r+1].y & 0xffff0000u);
            ae0 = fmaf(xe0, fmaf(kv[r].x,   he0 - le0, le0), ae0);
            ao0 = fmaf(xo0, fmaf(kv[r].x,   ho0 - lo0, lo0), ao0);
            ae1 = fmaf(xe1, fmaf(kv[r+1].x, he1 - le1, le1), ae1);
            ao1 = fmaf(xo1, fmaf(kv[r+1].x, ho1 - lo1, lo1), ao1);
        }
    }
    s_part[wv][2 * e]     = ae0 + ae1;
    s_part[wv][2 * e + 1] = ao0 + ao1;
    __syncthreads();
    if (t < FILTERS) {
        float s = 0.f;
        #pragma unroll
        for (int w8 = 0; w8 < 8; w8++) s += s_part[w8][t];
        s_agg[t] = s;
    }
    __syncthreads();
    // ---- x update: 128-dot split over 4 segments of 32 ----
    float v = 0.f;
    #pragma unroll 8
    for (int ff = seg * 32; ff < seg * 32 + 32; ff++)
        v = fmaf(s_agg[ff], w2[(size_t)ff * HIDDEN + c], v);
    s_red[seg][c] = v;
    __syncthreads();
    if (seg == 0) {
        float xnew = xold + b2[c] + s_red[0][c] + s_red[1][c] + s_red[2][c] + s_red[3][c];
        x[(size_t)j * HIDDEN + c] = xnew;
        s_xn[c] = xnew;
    }
    __syncthreads();
    if (!LAST) {
        float a2 = 0.f;
        #pragma unroll 8
        for (int hh = seg * 32; hh < seg * 32 + 32; hh++)
            a2 = fmaf(s_xn[hh], w1n[(size_t)hh * FILTERS + c], a2);
        s_red[seg][c] = a2;
        __syncthreads();
        if (seg == 0)
            xj_out[(size_t)j * FILTERS + c] =
                f2bf(b1n[c] + s_red[0][c] + s_red[1][c] + s_red[2][c] + s_red[3][c]);
    }
}

// ============ molecule pool + output MLP (R8 version, proven) ============
__global__ void __launch_bounds__(256) k_pool(const float* __restrict__ x,
        const int* __restrict__ batch, const float* __restrict__ ow1,
        const float* __restrict__ ob1, const float* __restrict__ ow2,
        const float* __restrict__ ob2, float* __restrict__ out) {
    int m = blockIdx.x, t = threadIdx.x;
    __shared__ float s_red[2][FILTERS];
    __shared__ float s_mol[HIDDEN];
    __shared__ float s_hh[64];
    __shared__ int   s_lo, s_cnt;
    if (t == 0) { s_lo = 0; s_cnt = 0; }
    __syncthreads();
    {
        int b0 = batch[t], b1 = batch[t + 256];
        atomicAdd(&s_lo,  (b0 <  m) + (b1 <  m));
        atomicAdd(&s_cnt, (b0 == m) + (b1 == m));
    }
    __syncthreads();
    int lo = s_lo, cnt = s_cnt, hi = lo + cnt;
    int f = t & 127, half = t >> 7;
    float s = 0.f;
    for (int i = lo + half; i < hi; i += 2) s += x[(size_t)i * HIDDEN + f];
    s_red[half][f] = s;
    __syncthreads();
    if (half == 0) s_mol[f] = (s_red[0][f] + s_red[1][f]) / (float)(cnt > 0 ? cnt : 1);
    __syncthreads();
    int o = t & 63, sl = t >> 6;
    float a = 0.f;
    #pragma unroll 8
    for (int h = sl * 32; h < sl * 32 + 32; h++) a = fmaf(s_mol[h], ow1[h * 64 + o], a);
    float* sr = (float*)s_red;
    __syncthreads();
    sr[sl * 64 + o] = a;
    __syncthreads();
    if (t < 64) {
        float v = ob1[t] + sr[t] + sr[64 + t] + sr[128 + t] + sr[192 + t];
        s_hh[t] = v / (1.f + __expf(-v));
    }
    __syncthreads();
    if (t < 64) {
        float v = s_hh[t] * ow2[t];
        for (int off = 32; off > 0; off >>= 1) v += __shfl_down(v, off, 64);
        if (t == 0) out[m] = v + ob2[0];
    }
}

extern "C" void kernel_launch(void* const* d_in, const int* in_sizes, int n_in,
                              void* d_out, int out_size, void* d_ws, size_t ws_size,
                              hipStream_t stream) {
    const int*   an    = (const int*)  d_in[0];
    const float* pos   = (const float*)d_in[1];
    const int*   batch = (const int*)  d_in[2];
    const float* emb   = (const float*)d_in[3];
    const float* fw1   = (const float*)d_in[4];
    const float* fb1   = (const float*)d_in[5];
    const float* fw2   = (const float*)d_in[6];
    const float* fb2   = (const float*)d_in[7];
    const float* d1w   = (const float*)d_in[8];
    const float* d1b   = (const float*)d_in[9];
    const float* d2w   = (const float*)d_in[10];
    const float* d2b   = (const float*)d_in[11];
    const float* ow1   = (const float*)d_in[12];
    const float* ob1   = (const float*)d_in[13];
    const float* ow2   = (const float*)d_in[14];
    const float* ob2   = (const float*)d_in[15];
    float* out = (float*)d_out;

    float*          x    = (float*)d_ws;                               // 256 KB
    unsigned short* xjA  = (unsigned short*)(x + N_ATOMS * HIDDEN);    // 128 KB
    unsigned short* xjB  = xjA + (size_t)N_ATOMS * FILTERS;            // 128 KB
    unsigned short* tab  = xjB + (size_t)N_ATOMS * FILTERS;            // 1.575 MB

    k_front<<<TWBLK + EMBB, 512, 0, stream>>>(
        an, emb, d1w, d1b, fw1, fb1, fw2, fb2, x, xjA, tab);

    const unsigned int* t0 = (const unsigned int*)(tab + (size_t)0 * PROWS * FILTERS * 2);
    const unsigned int* t1 = (const unsigned int*)(tab + (size_t)1 * PROWS * FILTERS * 2);
    const unsigned int* t2 = (const unsigned int*)(tab + (size_t)2 * PROWS * FILTERS * 2);

    k_layer<0><<<N_ATOMS, 512, 0, stream>>>(pos, t0, xjA, x,
        d2w + (size_t)0*FILTERS*HIDDEN, d2b + (size_t)0*HIDDEN,
        d1w + (size_t)1*HIDDEN*FILTERS, d1b + (size_t)1*FILTERS, xjB);
    k_layer<0><<<N_ATOMS, 512, 0, stream>>>(pos, t1, xjB, x,
        d2w + (size_t)1*FILTERS*HIDDEN, d2b + (size_t)1*HIDDEN,
        d1w + (size_t)2*HIDDEN*FILTERS, d1b + (size_t)2*FILTERS, xjA);
    k_layer<1><<<N_ATOMS, 512, 0, stream>>>(pos, t2, xjA, x,
        d2w + (size_t)2*FILTERS*HIDDEN, d2b + (size_t)2*HIDDEN,
        d1w, d1b, xjB);

    k_pool<<<N_MOL, 256, 0, stream>>>(x, batch, ow1, ob1, ow2, ob2, out);
}